// Round 4
// baseline (460.168 us; speedup 1.0000x reference)
//
#include <hip/hip_runtime.h>
#include <stdint.h>

// ============================================================================
// MultiHeadAttention fused pipeline (MI355X / gfx950)  — round 4
//   B=2, S=2048, D=1024, H=16, DEPTH=64
// Round-4 change (single variable): relax launch_bounds occupancy caps.
//   * pv_kernel  (256,4) -> (256,2): the 128-VGPR cap was forcing spill /
//     serialized prefetch (R2 failure signature). ~256 VGPR budget now.
//   * wts_kernel (256,4) -> (256,3): headroom above its ~120 live VGPRs.
// ============================================================================

typedef _Float16 half8 __attribute__((ext_vector_type(8)));
typedef float f32x4 __attribute__((ext_vector_type(4)));

#define MFMA16(a, b, c) __builtin_amdgcn_mfma_f32_16x16x32_f16((a), (b), (c), 0, 0, 0)

__device__ __forceinline__ void load_lds16(const void* g, void* l) {
  __builtin_amdgcn_global_load_lds(
      (const __attribute__((address_space(1))) void*)(uintptr_t)g,
      (__attribute__((address_space(3))) void*)(uintptr_t)l, 16, 0, 0);
}

// ---------------------------------------------------------------------------
// k0a: f32 -> f16 convert, 8 elems/thread, batched over 3 tensors
// ---------------------------------------------------------------------------
__global__ __launch_bounds__(256) void cvt_f16_kernel(
    const float* __restrict__ i0, const float* __restrict__ i1,
    const float* __restrict__ i2, _Float16* __restrict__ o0,
    _Float16* __restrict__ o1, _Float16* __restrict__ o2) {
  const float* in;
  _Float16* out;
  switch (blockIdx.y) {
    case 0: in = i0; out = o0; break;
    case 1: in = i1; out = o1; break;
    default: in = i2; out = o2; break;
  }
  const int i = blockIdx.x * 256 + threadIdx.x;
  const float4* p = (const float4*)in + 2 * (size_t)i;
  float4 a = p[0], b = p[1];
  half8 h;
  h[0] = (_Float16)a.x; h[1] = (_Float16)a.y; h[2] = (_Float16)a.z; h[3] = (_Float16)a.w;
  h[4] = (_Float16)b.x; h[5] = (_Float16)b.y; h[6] = (_Float16)b.z; h[7] = (_Float16)b.w;
  *((half8*)out + i) = h;
}

// ---------------------------------------------------------------------------
// k0b: w [1024x1024] f32 -> wT [1024x1024] f16, batched over 4 weights
// ---------------------------------------------------------------------------
__global__ __launch_bounds__(256) void transpose_cvt_kernel(
    const float* __restrict__ i0, const float* __restrict__ i1,
    const float* __restrict__ i2, const float* __restrict__ i3,
    _Float16* __restrict__ o0, _Float16* __restrict__ o1,
    _Float16* __restrict__ o2, _Float16* __restrict__ o3) {
  const float* in;
  _Float16* out;
  switch (blockIdx.z) {
    case 0: in = i0; out = o0; break;
    case 1: in = i1; out = o1; break;
    case 2: in = i2; out = o2; break;
    default: in = i3; out = o3; break;
  }
  __shared__ _Float16 tile[64][72];
  const int r  = threadIdx.x >> 2;
  const int c4 = threadIdx.x & 3;
  const int kin = blockIdx.y * 64, nin = blockIdx.x * 64;
#pragma unroll
  for (int i = 0; i < 4; ++i) {
    float4 v = *(const float4*)(in + (size_t)(kin + r) * 1024 + nin + c4 * 16 + i * 4);
    tile[c4 * 16 + i * 4 + 0][r] = (_Float16)v.x;
    tile[c4 * 16 + i * 4 + 1][r] = (_Float16)v.y;
    tile[c4 * 16 + i * 4 + 2][r] = (_Float16)v.z;
    tile[c4 * 16 + i * 4 + 3][r] = (_Float16)v.w;
  }
  __syncthreads();
#pragma unroll
  for (int i = 0; i < 4; ++i) {
    union { _Float16 hh[4]; uint2 u; } p;
    p.hh[0] = tile[r][c4 * 16 + i * 4 + 0];
    p.hh[1] = tile[r][c4 * 16 + i * 4 + 1];
    p.hh[2] = tile[r][c4 * 16 + i * 4 + 2];
    p.hh[3] = tile[r][c4 * 16 + i * 4 + 3];
    *(uint2*)(out + (size_t)(nin + r) * 1024 + kin + c4 * 16 + i * 4) = p.u;
  }
}

// ---------------------------------------------------------------------------
// k1/k3: 128x128-tile f16 GEMM (unchanged)
// ---------------------------------------------------------------------------
struct GemmArgs {
  const _Float16* A[3];
  const _Float16* BT[3];
  const float* bias[3];
  void* out[3];
};

__global__ __launch_bounds__(256, 2) void gemm_f16_kernel(GemmArgs ga, int K,
                                                          int modes) {
  const _Float16* __restrict__ A  = ga.A[blockIdx.z];
  const _Float16* __restrict__ BT = ga.BT[blockIdx.z];
  const float* __restrict__ bias  = ga.bias[blockIdx.z];
  void* __restrict__ out          = ga.out[blockIdx.z];
  const int MODE = (modes >> (4 * blockIdx.z)) & 15;

  __shared__ __align__(16) _Float16 As[128 * 32];
  __shared__ __align__(16) _Float16 Bs[128 * 32];
  const int tid = threadIdx.x;
  const int w = tid >> 6, l = tid & 63;
  const int g = l >> 4, c = l & 15;
  const int tm = blockIdx.y * 128, tn = blockIdx.x * 128;
  const int wr = w >> 1, wc = w & 1;

  f32x4 acc[4][4];
#pragma unroll
  for (int i = 0; i < 4; ++i)
#pragma unroll
    for (int j = 0; j < 4; ++j) acc[i][j] = (f32x4){0.f, 0.f, 0.f, 0.f};

  const int srow0 = w * 16 + (l >> 2);
  const int sl = l & 3;

  for (int kt = 0; kt < K; kt += 32) {
#pragma unroll
    for (int r = 0; r < 2; ++r) {
      const int row = r * 64 + srow0;
      const int kc = sl ^ ((row >> 1) & 3);
      load_lds16(A + (size_t)(tm + row) * K + kt + kc * 8, As + row * 32 + sl * 8);
      load_lds16(BT + (size_t)(tn + row) * K + kt + kc * 8, Bs + row * 32 + sl * 8);
    }
    __syncthreads();
    half8 af[4], bf[4];
#pragma unroll
    for (int mt = 0; mt < 4; ++mt) {
      const int row = wr * 64 + mt * 16 + c;
      af[mt] = *(const half8*)(As + row * 32 + (g ^ ((row >> 1) & 3)) * 8);
    }
#pragma unroll
    for (int nt = 0; nt < 4; ++nt) {
      const int row = wc * 64 + nt * 16 + c;
      bf[nt] = *(const half8*)(Bs + row * 32 + (g ^ ((row >> 1) & 3)) * 8);
    }
#pragma unroll
    for (int mt = 0; mt < 4; ++mt)
#pragma unroll
      for (int nt = 0; nt < 4; ++nt)
        acc[mt][nt] = MFMA16(af[mt], bf[nt], acc[mt][nt]);
    __syncthreads();
  }

#pragma unroll
  for (int mt = 0; mt < 4; ++mt) {
#pragma unroll
    for (int nt = 0; nt < 4; ++nt) {
      const int n = tn + wc * 64 + nt * 16 + c;
      const float bv = bias[n];
      if (MODE == 2) {
#pragma unroll
        for (int r = 0; r < 4; ++r) {
          const int m = tm + wr * 64 + mt * 16 + 4 * g + r;
          ((float*)out)[(size_t)m * 1024 + n] = acc[mt][nt][r] + bv;
        }
      } else if (MODE == 0) {
        const int h_ = n >> 6, d_ = n & 63;
#pragma unroll
        for (int r = 0; r < 4; ++r) {
          const int m = tm + wr * 64 + mt * 16 + 4 * g + r;
          const int b_ = m >> 11, s_ = m & 2047;
          ((_Float16*)out)[((size_t)(b_ * 16 + h_) * 2048 + s_) * 64 + d_] =
              (_Float16)(acc[mt][nt][r] + bv);
        }
      } else {
        const int h_ = n >> 6, d_ = n & 63;
        const int m0 = tm + wr * 64 + mt * 16 + 4 * g;
        const int b_ = m0 >> 11, s0 = m0 & 2047;
        union { _Float16 hh[4]; uint2 u; } p;
#pragma unroll
        for (int r = 0; r < 4; ++r) p.hh[r] = (_Float16)(acc[mt][nt][r] + bv);
        *(uint2*)((_Float16*)out + ((size_t)(b_ * 16 + h_) * 64 + d_) * 2048 + s0) = p.u;
      }
    }
  }
}

// ---------------------------------------------------------------------------
// pv_kernel: PV + row-sums. Block = (qt 16 rows, h, b), 4 waves, wave w owns
// k-cols [w*512,(w+1)*512). Swapped QK^T -> register P -> shfl fixup -> PV.
// (256,2): ~256 VGPR budget, full prefetch ILP, no spill.
// ---------------------------------------------------------------------------
__global__ __launch_bounds__(256, 2) void pv_kernel(
    const _Float16* __restrict__ qh,   // [BH, S, 64]
    const _Float16* __restrict__ kh,   // [BH, S, 64]
    const _Float16* __restrict__ vT,   // [BH, 64, S]
    float* __restrict__ invp,          // [BH, S]
    _Float16* __restrict__ concat) {   // [B*S, 1024]
  __shared__ __align__(16) float part[4][16][68];
  __shared__ float red[64];
  const int tid = threadIdx.x;
  const int w = tid >> 6, l = tid & 63;
  const int g = l >> 4, c = l & 15;
  const int qt = blockIdx.x, h = blockIdx.y, b = blockIdx.z;
  const int bh = b * 16 + h;
  const _Float16* qp = qh + ((size_t)bh * 2048 + qt * 16) * 64;
  const _Float16* kp = kh + (size_t)bh * 2048 * 64;
  const _Float16* vp = vT + (size_t)bh * 64 * 2048;
  const int kbase = w * 512;

  const half8 aq0 = *(const half8*)(qp + (size_t)c * 64 + 8 * g);
  const half8 aq1 = *(const half8*)(qp + (size_t)c * 64 + 32 + 8 * g);

  f32x4 pv0 = {0.f, 0.f, 0.f, 0.f}, pv1 = {0.f, 0.f, 0.f, 0.f};
  f32x4 pv2 = {0.f, 0.f, 0.f, 0.f}, pv3 = {0.f, 0.f, 0.f, 0.f};
  float sum = 0.f;

  half8 kf0 = *(const half8*)(kp + (size_t)(kbase + c) * 64 + 8 * g);
  half8 kf1 = *(const half8*)(kp + (size_t)(kbase + c) * 64 + 32 + 8 * g);
  half8 kf2 = *(const half8*)(kp + (size_t)(kbase + 16 + c) * 64 + 8 * g);
  half8 kf3 = *(const half8*)(kp + (size_t)(kbase + 16 + c) * 64 + 32 + 8 * g);

  const int L01 = (2 * (g & 1)) * 16 + c;
  const int L23 = L01 + 16;
  const bool lohalf = (g < 2);

#pragma unroll 2
  for (int ch = 0; ch < 16; ++ch) {
    const int kb = kbase + ch * 32;
    const int nkb = kbase + ((ch < 15) ? (ch + 1) * 32 : 0);
    half8 nk0 = *(const half8*)(kp + (size_t)(nkb + c) * 64 + 8 * g);
    half8 nk1 = *(const half8*)(kp + (size_t)(nkb + c) * 64 + 32 + 8 * g);
    half8 nk2 = *(const half8*)(kp + (size_t)(nkb + 16 + c) * 64 + 8 * g);
    half8 nk3 = *(const half8*)(kp + (size_t)(nkb + 16 + c) * 64 + 32 + 8 * g);
    half8 vf0 = *(const half8*)(vp + (size_t)(0 * 16 + c) * 2048 + kb + 8 * g);
    half8 vf1 = *(const half8*)(vp + (size_t)(1 * 16 + c) * 2048 + kb + 8 * g);
    half8 vf2 = *(const half8*)(vp + (size_t)(2 * 16 + c) * 2048 + kb + 8 * g);
    half8 vf3 = *(const half8*)(vp + (size_t)(3 * 16 + c) * 2048 + kb + 8 * g);

    f32x4 sA = {0.f, 0.f, 0.f, 0.f}, sB = {0.f, 0.f, 0.f, 0.f};
    sA = MFMA16(kf0, aq0, sA);
    sA = MFMA16(kf1, aq1, sA);
    sB = MFMA16(kf2, aq0, sB);
    sB = MFMA16(kf3, aq1, sB);

    float eA[4], eB[4];
#pragma unroll
    for (int r = 0; r < 4; ++r) {
      eA[r] = __expf(sA[r] * 0.125f);
      eB[r] = __expf(sB[r] * 0.125f);
      sum += eA[r] + eB[r];
    }
    union { _Float16 h2[2]; unsigned u; } p0, p1, p2, p3;
    p0.h2[0] = (_Float16)eA[0]; p0.h2[1] = (_Float16)eA[1];
    p1.h2[0] = (_Float16)eA[2]; p1.h2[1] = (_Float16)eA[3];
    p2.h2[0] = (_Float16)eB[0]; p2.h2[1] = (_Float16)eB[1];
    p3.h2[0] = (_Float16)eB[2]; p3.h2[1] = (_Float16)eB[3];
    unsigned s0a = __shfl(p0.u, L01, 64), s0b = __shfl(p2.u, L01, 64);
    unsigned s1a = __shfl(p1.u, L01, 64), s1b = __shfl(p3.u, L01, 64);
    unsigned s2a = __shfl(p0.u, L23, 64), s2b = __shfl(p2.u, L23, 64);
    unsigned s3a = __shfl(p1.u, L23, 64), s3b = __shfl(p3.u, L23, 64);
    union { unsigned u[4]; half8 h; } aw;
    aw.u[0] = lohalf ? s0a : s0b;
    aw.u[1] = lohalf ? s1a : s1b;
    aw.u[2] = lohalf ? s2a : s2b;
    aw.u[3] = lohalf ? s3a : s3b;

    pv0 = MFMA16(aw.h, vf0, pv0);
    pv1 = MFMA16(aw.h, vf1, pv1);
    pv2 = MFMA16(aw.h, vf2, pv2);
    pv3 = MFMA16(aw.h, vf3, pv3);

    kf0 = nk0; kf1 = nk1; kf2 = nk2; kf3 = nk3;
  }

  sum += __shfl_xor(sum, 16, 64);
  sum += __shfl_xor(sum, 32, 64);
  if (l < 16) red[w * 16 + l] = sum;

#pragma unroll
  for (int r = 0; r < 4; ++r) {
    part[w][4 * g + r][0 * 16 + c] = pv0[r];
    part[w][4 * g + r][1 * 16 + c] = pv1[r];
    part[w][4 * g + r][2 * 16 + c] = pv2[r];
    part[w][4 * g + r][3 * 16 + c] = pv3[r];
  }
  __syncthreads();

  const int qq = tid & 15, dbase = (tid >> 4) * 4;
  const float tot = red[qq] + red[16 + qq] + red[32 + qq] + red[48 + qq];
  const float inv = 1.0f / tot;
  if (tid < 16) invp[(size_t)bh * 2048 + qt * 16 + tid] = inv;
  union { _Float16 hh[4]; uint2 u2; } pk;
#pragma unroll
  for (int i = 0; i < 4; ++i) {
    const int d = dbase + i;
    pk.hh[i] = (_Float16)((part[0][qq][d] + part[1][qq][d] +
                           part[2][qq][d] + part[3][qq][d]) * inv);
  }
  *(uint2*)(concat + (size_t)(b * 2048 + qt * 16 + qq) * 1024 + h * 64 + dbase) = pk.u2;
}

// ---------------------------------------------------------------------------
// wts_kernel: weights = exp(QK^T/8) * inv[q]  -> [BH,S,S] f32, nt stores.
// (256,3): ~170 VGPR cap, clear of the ~120 live.
// ---------------------------------------------------------------------------
__global__ __launch_bounds__(256, 3) void wts_kernel(
    const _Float16* __restrict__ qh, const _Float16* __restrict__ kh,
    const float* __restrict__ invp, float* __restrict__ wout) {
  __shared__ __align__(16) _Float16 Qs[128 * 64];
  __shared__ __align__(16) _Float16 Ks[128 * 64];
  __shared__ float invs[128];
  const int tid = threadIdx.x;
  const int w = tid >> 6, l = tid & 63;
  const int g = l >> 4, c = l & 15;
  const int tk = blockIdx.x * 128, tq = blockIdx.y * 128;
  const int bh = blockIdx.z;
  const _Float16* qg = qh + ((size_t)bh * 2048 + tq) * 64;
  const _Float16* kg = kh + ((size_t)bh * 2048 + tk) * 64;

  if (tid < 128) invs[tid] = invp[(size_t)bh * 2048 + tq + tid];

#pragma unroll
  for (int rnd = 0; rnd < 4; ++rnd) {
    const int seg = w * 4 + rnd;
    const int row = seg * 8 + (l >> 3);
    const int ss = (l & 7) ^ (row & 7);
    load_lds16(qg + (size_t)row * 64 + ss * 8, Qs + seg * 512 + l * 8);
    load_lds16(kg + (size_t)row * 64 + ss * 8, Ks + seg * 512 + l * 8);
  }
  __syncthreads();

  const int wr = w >> 1, wc = w & 1;
  f32x4 acc[4][4];
#pragma unroll
  for (int i = 0; i < 4; ++i)
#pragma unroll
    for (int j = 0; j < 4; ++j) acc[i][j] = (f32x4){0.f, 0.f, 0.f, 0.f};

#pragma unroll
  for (int dh = 0; dh < 2; ++dh) {
    half8 af[4], bf[4];
#pragma unroll
    for (int mt = 0; mt < 4; ++mt) {
      const int row = wr * 64 + mt * 16 + c;
      af[mt] = *(const half8*)(Qs + row * 64 + (((dh * 4 + g) ^ (row & 7)) * 8));
    }
#pragma unroll
    for (int nt = 0; nt < 4; ++nt) {
      const int row = wc * 64 + nt * 16 + c;
      bf[nt] = *(const half8*)(Ks + row * 64 + (((dh * 4 + g) ^ (row & 7)) * 8));
    }
#pragma unroll
    for (int mt = 0; mt < 4; ++mt)
#pragma unroll
      for (int nt = 0; nt < 4; ++nt)
        acc[mt][nt] = MFMA16(af[mt], bf[nt], acc[mt][nt]);
  }

#pragma unroll
  for (int mt = 0; mt < 4; ++mt) {
#pragma unroll
    for (int r = 0; r < 4; ++r) {
      const int qrow = wr * 64 + mt * 16 + 4 * g + r;
      const float iv = invs[qrow];
      float* wr_ = wout + ((size_t)bh * 2048 + tq + qrow) * 2048 + tk;
#pragma unroll
      for (int nt = 0; nt < 4; ++nt) {
        const int kcol = wc * 64 + nt * 16 + c;
        __builtin_nontemporal_store(__expf(acc[mt][nt][r] * 0.125f) * iv,
                                    wr_ + kcol);
      }
    }
  }
}

// ---------------------------------------------------------------------------
extern "C" void kernel_launch(void* const* d_in, const int* in_sizes, int n_in,
                              void* d_out, int out_size, void* d_ws, size_t ws_size,
                              hipStream_t stream) {
  const float* Q  = (const float*)d_in[0];
  const float* Kx = (const float*)d_in[1];
  const float* V  = (const float*)d_in[2];
  const float* wq = (const float*)d_in[3];
  const float* bq = (const float*)d_in[4];
  const float* wk = (const float*)d_in[5];
  const float* bk = (const float*)d_in[6];
  const float* wv = (const float*)d_in[7];
  const float* bv = (const float*)d_in[8];
  const float* wo = (const float*)d_in[9];
  const float* bo = (const float*)d_in[10];

  float* out  = (float*)d_out;
  float* wout = out + (size_t)4194304;

  char* ws = (char*)d_ws;
  const size_t MB = 1024 * 1024;
  _Float16* Xq  = (_Float16*)(ws + 0 * MB);
  _Float16* Xk  = (_Float16*)(ws + 8 * MB);
  _Float16* Xv  = (_Float16*)(ws + 16 * MB);
  _Float16* wqT = (_Float16*)(ws + 24 * MB);
  _Float16* wkT = (_Float16*)(ws + 26 * MB);
  _Float16* wvT = (_Float16*)(ws + 28 * MB);
  _Float16* woT = (_Float16*)(ws + 30 * MB);
  _Float16* qhp = (_Float16*)(ws + 32 * MB);
  _Float16* khp = (_Float16*)(ws + 40 * MB);
  _Float16* vTp = (_Float16*)(ws + 48 * MB);
  _Float16* cat = (_Float16*)(ws + 56 * MB);
  float*    invp = (float*)(ws + 16 * MB);  // reuses Xv (dead after QKV GEMM)

  cvt_f16_kernel<<<dim3(2048, 3), 256, 0, stream>>>(Q, Kx, V, Xq, Xk, Xv);
  transpose_cvt_kernel<<<dim3(16, 16, 4), 256, 0, stream>>>(
      wq, wk, wv, wo, wqT, wkT, wvT, woT);

  GemmArgs qkv;
  qkv.A[0] = Xq;  qkv.A[1] = Xk;  qkv.A[2] = Xv;
  qkv.BT[0] = wqT; qkv.BT[1] = wkT; qkv.BT[2] = wvT;
  qkv.bias[0] = bq; qkv.bias[1] = bk; qkv.bias[2] = bv;
  qkv.out[0] = qhp; qkv.out[1] = khp; qkv.out[2] = vTp;
  gemm_f16_kernel<<<dim3(8, 32, 3), 256, 0, stream>>>(qkv, 1024, 0x100);

  pv_kernel<<<dim3(128, 16, 2), 256, 0, stream>>>(qhp, khp, vTp, invp, cat);
  wts_kernel<<<dim3(16, 16, 32), 256, 0, stream>>>(qhp, khp, invp, wout);

  GemmArgs og;
  og.A[0] = cat; og.A[1] = cat; og.A[2] = cat;
  og.BT[0] = woT; og.BT[1] = woT; og.BT[2] = woT;
  og.bias[0] = bo; og.bias[1] = bo; og.bias[2] = bo;
  og.out[0] = out; og.out[1] = out; og.out[2] = out;
  gemm_f16_kernel<<<dim3(8, 32, 1), 256, 0, stream>>>(og, 1024, 0x2);
}

// Round 6
// 406.640 us; speedup vs baseline: 1.1316x; 1.1316x over previous
//
#include <hip/hip_runtime.h>
#include <stdint.h>

// ============================================================================
// MultiHeadAttention fused pipeline (MI355X / gfx950)  — round 6
//   B=2, S=2048, D=1024, H=16, DEPTH=64
// Round-6 = round-5 with the compile fix: nt stores use clang ext-vector
// f32x4 (HIP float4 struct is rejected by __builtin_nontemporal_store).
//   * pv_kernel: 64 q-rows/block; K/V staged ONCE into LDS per chunk,
//     shared by 4 waves -> 4x less global re-read.
//   * wts_kernel: epilogue stages 32x128 f32 chunks in LDS, then streams
//     coalesced f32x4 nt stores.
// ============================================================================

typedef _Float16 half8 __attribute__((ext_vector_type(8)));
typedef float f32x4 __attribute__((ext_vector_type(4)));

#define MFMA16(a, b, c) __builtin_amdgcn_mfma_f32_16x16x32_f16((a), (b), (c), 0, 0, 0)

__device__ __forceinline__ void load_lds16(const void* g, void* l) {
  __builtin_amdgcn_global_load_lds(
      (const __attribute__((address_space(1))) void*)(uintptr_t)g,
      (__attribute__((address_space(3))) void*)(uintptr_t)l, 16, 0, 0);
}

// ---------------------------------------------------------------------------
// k0a: f32 -> f16 convert, 8 elems/thread, batched over 3 tensors
// ---------------------------------------------------------------------------
__global__ __launch_bounds__(256) void cvt_f16_kernel(
    const float* __restrict__ i0, const float* __restrict__ i1,
    const float* __restrict__ i2, _Float16* __restrict__ o0,
    _Float16* __restrict__ o1, _Float16* __restrict__ o2) {
  const float* in;
  _Float16* out;
  switch (blockIdx.y) {
    case 0: in = i0; out = o0; break;
    case 1: in = i1; out = o1; break;
    default: in = i2; out = o2; break;
  }
  const int i = blockIdx.x * 256 + threadIdx.x;
  const float4* p = (const float4*)in + 2 * (size_t)i;
  float4 a = p[0], b = p[1];
  half8 h;
  h[0] = (_Float16)a.x; h[1] = (_Float16)a.y; h[2] = (_Float16)a.z; h[3] = (_Float16)a.w;
  h[4] = (_Float16)b.x; h[5] = (_Float16)b.y; h[6] = (_Float16)b.z; h[7] = (_Float16)b.w;
  *((half8*)out + i) = h;
}

// ---------------------------------------------------------------------------
// k0b: w [1024x1024] f32 -> wT [1024x1024] f16, batched over 4 weights
// ---------------------------------------------------------------------------
__global__ __launch_bounds__(256) void transpose_cvt_kernel(
    const float* __restrict__ i0, const float* __restrict__ i1,
    const float* __restrict__ i2, const float* __restrict__ i3,
    _Float16* __restrict__ o0, _Float16* __restrict__ o1,
    _Float16* __restrict__ o2, _Float16* __restrict__ o3) {
  const float* in;
  _Float16* out;
  switch (blockIdx.z) {
    case 0: in = i0; out = o0; break;
    case 1: in = i1; out = o1; break;
    case 2: in = i2; out = o2; break;
    default: in = i3; out = o3; break;
  }
  __shared__ _Float16 tile[64][72];
  const int r  = threadIdx.x >> 2;
  const int c4 = threadIdx.x & 3;
  const int kin = blockIdx.y * 64, nin = blockIdx.x * 64;
#pragma unroll
  for (int i = 0; i < 4; ++i) {
    float4 v = *(const float4*)(in + (size_t)(kin + r) * 1024 + nin + c4 * 16 + i * 4);
    tile[c4 * 16 + i * 4 + 0][r] = (_Float16)v.x;
    tile[c4 * 16 + i * 4 + 1][r] = (_Float16)v.y;
    tile[c4 * 16 + i * 4 + 2][r] = (_Float16)v.z;
    tile[c4 * 16 + i * 4 + 3][r] = (_Float16)v.w;
  }
  __syncthreads();
#pragma unroll
  for (int i = 0; i < 4; ++i) {
    union { _Float16 hh[4]; uint2 u; } p;
    p.hh[0] = tile[r][c4 * 16 + i * 4 + 0];
    p.hh[1] = tile[r][c4 * 16 + i * 4 + 1];
    p.hh[2] = tile[r][c4 * 16 + i * 4 + 2];
    p.hh[3] = tile[r][c4 * 16 + i * 4 + 3];
    *(uint2*)(out + (size_t)(nin + r) * 1024 + kin + c4 * 16 + i * 4) = p.u;
  }
}

// ---------------------------------------------------------------------------
// k1/k3: 128x128-tile f16 GEMM (unchanged)
// ---------------------------------------------------------------------------
struct GemmArgs {
  const _Float16* A[3];
  const _Float16* BT[3];
  const float* bias[3];
  void* out[3];
};

__global__ __launch_bounds__(256, 2) void gemm_f16_kernel(GemmArgs ga, int K,
                                                          int modes) {
  const _Float16* __restrict__ A  = ga.A[blockIdx.z];
  const _Float16* __restrict__ BT = ga.BT[blockIdx.z];
  const float* __restrict__ bias  = ga.bias[blockIdx.z];
  void* __restrict__ out          = ga.out[blockIdx.z];
  const int MODE = (modes >> (4 * blockIdx.z)) & 15;

  __shared__ __align__(16) _Float16 As[128 * 32];
  __shared__ __align__(16) _Float16 Bs[128 * 32];
  const int tid = threadIdx.x;
  const int w = tid >> 6, l = tid & 63;
  const int g = l >> 4, c = l & 15;
  const int tm = blockIdx.y * 128, tn = blockIdx.x * 128;
  const int wr = w >> 1, wc = w & 1;

  f32x4 acc[4][4];
#pragma unroll
  for (int i = 0; i < 4; ++i)
#pragma unroll
    for (int j = 0; j < 4; ++j) acc[i][j] = (f32x4){0.f, 0.f, 0.f, 0.f};

  const int srow0 = w * 16 + (l >> 2);
  const int sl = l & 3;

  for (int kt = 0; kt < K; kt += 32) {
#pragma unroll
    for (int r = 0; r < 2; ++r) {
      const int row = r * 64 + srow0;
      const int kc = sl ^ ((row >> 1) & 3);
      load_lds16(A + (size_t)(tm + row) * K + kt + kc * 8, As + row * 32 + sl * 8);
      load_lds16(BT + (size_t)(tn + row) * K + kt + kc * 8, Bs + row * 32 + sl * 8);
    }
    __syncthreads();
    half8 af[4], bf[4];
#pragma unroll
    for (int mt = 0; mt < 4; ++mt) {
      const int row = wr * 64 + mt * 16 + c;
      af[mt] = *(const half8*)(As + row * 32 + (g ^ ((row >> 1) & 3)) * 8);
    }
#pragma unroll
    for (int nt = 0; nt < 4; ++nt) {
      const int row = wc * 64 + nt * 16 + c;
      bf[nt] = *(const half8*)(Bs + row * 32 + (g ^ ((row >> 1) & 3)) * 8);
    }
#pragma unroll
    for (int mt = 0; mt < 4; ++mt)
#pragma unroll
      for (int nt = 0; nt < 4; ++nt)
        acc[mt][nt] = MFMA16(af[mt], bf[nt], acc[mt][nt]);
    __syncthreads();
  }

#pragma unroll
  for (int mt = 0; mt < 4; ++mt) {
#pragma unroll
    for (int nt = 0; nt < 4; ++nt) {
      const int n = tn + wc * 64 + nt * 16 + c;
      const float bv = bias[n];
      if (MODE == 2) {
#pragma unroll
        for (int r = 0; r < 4; ++r) {
          const int m = tm + wr * 64 + mt * 16 + 4 * g + r;
          ((float*)out)[(size_t)m * 1024 + n] = acc[mt][nt][r] + bv;
        }
      } else if (MODE == 0) {
        const int h_ = n >> 6, d_ = n & 63;
#pragma unroll
        for (int r = 0; r < 4; ++r) {
          const int m = tm + wr * 64 + mt * 16 + 4 * g + r;
          const int b_ = m >> 11, s_ = m & 2047;
          ((_Float16*)out)[((size_t)(b_ * 16 + h_) * 2048 + s_) * 64 + d_] =
              (_Float16)(acc[mt][nt][r] + bv);
        }
      } else {
        const int h_ = n >> 6, d_ = n & 63;
        const int m0 = tm + wr * 64 + mt * 16 + 4 * g;
        const int b_ = m0 >> 11, s0 = m0 & 2047;
        union { _Float16 hh[4]; uint2 u; } p;
#pragma unroll
        for (int r = 0; r < 4; ++r) p.hh[r] = (_Float16)(acc[mt][nt][r] + bv);
        *(uint2*)((_Float16*)out + ((size_t)(b_ * 16 + h_) * 64 + d_) * 2048 + s0) = p.u;
      }
    }
  }
}

// ---------------------------------------------------------------------------
// pv_kernel v2: block = (qt of 64 rows, h, b), 4 waves; wave w owns q-rows
// [qt*64+w*16, +16) over ALL 2048 k. K/V staged per 64-k chunk into shared
// LDS (8KB+8KB, XOR-swizzled) -> 4 waves share one global read.
// Swapped QK^T (register P) -> shfl fixup -> PV. Outputs concat + invp.
// ---------------------------------------------------------------------------
__global__ __launch_bounds__(256, 3) void pv_kernel(
    const _Float16* __restrict__ qh,   // [BH, S, 64]
    const _Float16* __restrict__ kh,   // [BH, S, 64]
    const _Float16* __restrict__ vT,   // [BH, 64, S]
    float* __restrict__ invp,          // [BH, S]
    _Float16* __restrict__ concat) {   // [B*S, 1024]
  __shared__ __align__(16) _Float16 Ksh[64 * 64];   // [krow][8 slots of 8 f16]
  __shared__ __align__(16) _Float16 Vsh[64 * 64];   // [drow][8 slots]
  __shared__ __align__(16) float part[4][16][68];
  const int tid = threadIdx.x;
  const int w = tid >> 6, l = tid & 63;
  const int g = l >> 4, c = l & 15;
  const int qt = blockIdx.x, h = blockIdx.y, b = blockIdx.z;
  const int bh = b * 16 + h;
  const int q0 = qt * 64 + w * 16;  // this wave's q-base
  const _Float16* qp = qh + ((size_t)bh * 2048 + q0) * 64;
  const _Float16* kp = kh + (size_t)bh * 2048 * 64;
  const _Float16* vp = vT + (size_t)bh * 64 * 2048;

  // Q B-frags: lane holds Q[q=c][d=8g+j], two d-halves
  const half8 aq0 = *(const half8*)(qp + (size_t)c * 64 + 8 * g);
  const half8 aq1 = *(const half8*)(qp + (size_t)c * 64 + 32 + 8 * g);

  f32x4 pv0 = {0.f,0.f,0.f,0.f}, pv1 = {0.f,0.f,0.f,0.f};
  f32x4 pv2 = {0.f,0.f,0.f,0.f}, pv3 = {0.f,0.f,0.f,0.f};
  float sum = 0.f;

  const int L01 = (2 * (g & 1)) * 16 + c;
  const int L23 = L01 + 16;
  const bool lohalf = (g < 2);

  // staging indices (same for every chunk)
  const int n0 = tid, n1 = tid + 256;
  const int r0 = n0 >> 3, s0 = n0 & 7, z0 = (s0 ^ (r0 & 7)) * 8;
  const int r1 = n1 >> 3, s1 = n1 & 7, z1 = (s1 ^ (r1 & 7)) * 8;

#pragma unroll 1
  for (int kc = 0; kc < 2048; kc += 64) {
    // ---- stage K[kc..kc+64][0..64] and V[0..64][kc..kc+64] (swizzled src) --
    load_lds16(kp + (size_t)(kc + r0) * 64 + z0, Ksh + n0 * 8);
    load_lds16(kp + (size_t)(kc + r1) * 64 + z1, Ksh + n1 * 8);
    load_lds16(vp + (size_t)r0 * 2048 + kc + z0, Vsh + n0 * 8);
    load_lds16(vp + (size_t)r1 * 2048 + kc + z1, Vsh + n1 * 8);
    __syncthreads();

    // ---- 4 S^T tiles: lane (g,c) holds S^T[k=16t+4g+r][q=c] -------------
    float e[16];
#pragma unroll
    for (int t = 0; t < 4; ++t) {
      const int krow = t * 16 + c;
      const int swz = krow & 7;
      half8 k0 = *(const half8*)(Ksh + krow * 64 + ((g ^ swz) * 8));
      half8 k1 = *(const half8*)(Ksh + krow * 64 + (((4 + g) ^ swz) * 8));
      f32x4 s = {0.f, 0.f, 0.f, 0.f};
      s = MFMA16(k0, aq0, s);
      s = MFMA16(k1, aq1, s);
#pragma unroll
      for (int r = 0; r < 4; ++r) {
        e[t * 4 + r] = __expf(s[r] * 0.125f);
        sum += e[t * 4 + r];
      }
    }

    // ---- two 32-k halves: fixup -> P A-frag, then PV MFMAs ---------------
#pragma unroll
    for (int kh2 = 0; kh2 < 2; ++kh2) {
      union { _Float16 h2[2]; unsigned u; } p0, p1, p2, p3;
      p0.h2[0] = (_Float16)e[kh2*8+0]; p0.h2[1] = (_Float16)e[kh2*8+1];
      p1.h2[0] = (_Float16)e[kh2*8+2]; p1.h2[1] = (_Float16)e[kh2*8+3];
      p2.h2[0] = (_Float16)e[kh2*8+4]; p2.h2[1] = (_Float16)e[kh2*8+5];
      p3.h2[0] = (_Float16)e[kh2*8+6]; p3.h2[1] = (_Float16)e[kh2*8+7];
      unsigned s0a = __shfl(p0.u, L01, 64), s0b = __shfl(p2.u, L01, 64);
      unsigned s1a = __shfl(p1.u, L01, 64), s1b = __shfl(p3.u, L01, 64);
      unsigned s2a = __shfl(p0.u, L23, 64), s2b = __shfl(p2.u, L23, 64);
      unsigned s3a = __shfl(p1.u, L23, 64), s3b = __shfl(p3.u, L23, 64);
      union { unsigned u[4]; half8 h; } aw;
      aw.u[0] = lohalf ? s0a : s0b;
      aw.u[1] = lohalf ? s1a : s1b;
      aw.u[2] = lohalf ? s2a : s2b;
      aw.u[3] = lohalf ? s3a : s3b;

      {
        const int d0 = 0 * 16 + c, d1 = 1 * 16 + c, d2 = 2 * 16 + c, d3 = 3 * 16 + c;
        half8 v0 = *(const half8*)(Vsh + d0 * 64 + (((kh2 * 4 + g) ^ (d0 & 7)) * 8));
        half8 v1 = *(const half8*)(Vsh + d1 * 64 + (((kh2 * 4 + g) ^ (d1 & 7)) * 8));
        half8 v2 = *(const half8*)(Vsh + d2 * 64 + (((kh2 * 4 + g) ^ (d2 & 7)) * 8));
        half8 v3 = *(const half8*)(Vsh + d3 * 64 + (((kh2 * 4 + g) ^ (d3 & 7)) * 8));
        pv0 = MFMA16(aw.h, v0, pv0);
        pv1 = MFMA16(aw.h, v1, pv1);
        pv2 = MFMA16(aw.h, v2, pv2);
        pv3 = MFMA16(aw.h, v3, pv3);
      }
    }
    __syncthreads();  // before next chunk's stage overwrites Ksh/Vsh
  }

  // ---- per-wave row sums (full k coverage): reduce over g-groups ---------
  sum += __shfl_xor(sum, 16, 64);
  sum += __shfl_xor(sum, 32, 64);
  const float inv_c = 1.0f / sum;             // inv for q = q0 + c
  if (l < 16) invp[(size_t)bh * 2048 + q0 + l] = inv_c;
  float invr[4];
#pragma unroll
  for (int r = 0; r < 4; ++r) invr[r] = __shfl(inv_c, 4 * g + r, 64);

  // ---- pack via per-wave LDS transpose, store concat f16 -----------------
#pragma unroll
  for (int r = 0; r < 4; ++r) {
    part[w][4 * g + r][0 * 16 + c] = pv0[r] * invr[r];
    part[w][4 * g + r][1 * 16 + c] = pv1[r] * invr[r];
    part[w][4 * g + r][2 * 16 + c] = pv2[r] * invr[r];
    part[w][4 * g + r][3 * 16 + c] = pv3[r] * invr[r];
  }
  __syncthreads();
  {
    const int ql = l & 15, dh2 = l >> 4;  // 16 d per lane
    union { _Float16 hh[8]; uint4 u4; } pk;
#pragma unroll
    for (int half = 0; half < 2; ++half) {
#pragma unroll
      for (int i = 0; i < 8; ++i)
        pk.hh[i] = (_Float16)part[w][ql][dh2 * 16 + half * 8 + i];
      *(uint4*)(concat + (size_t)(b * 2048 + q0 + ql) * 1024 + h * 64 +
                dh2 * 16 + half * 8) = pk.u4;
    }
  }
}

// ---------------------------------------------------------------------------
// wts_kernel: weights = exp(QK^T/8)*inv[q] -> [BH,S,S] f32.
// Epilogue: stage 32x128 f32 chunks in LDS, stream coalesced f32x4 nt stores.
// ---------------------------------------------------------------------------
__global__ __launch_bounds__(256, 3) void wts_kernel(
    const _Float16* __restrict__ qh, const _Float16* __restrict__ kh,
    const float* __restrict__ invp, float* __restrict__ wout) {
  __shared__ __align__(16) _Float16 Qs[128 * 64];
  __shared__ __align__(16) _Float16 Ks[128 * 64];
  __shared__ __align__(16) float stg[32][132];
  __shared__ float invs[128];
  const int tid = threadIdx.x;
  const int w = tid >> 6, l = tid & 63;
  const int g = l >> 4, c = l & 15;
  const int tk = blockIdx.x * 128, tq = blockIdx.y * 128;
  const int bh = blockIdx.z;
  const _Float16* qg = qh + ((size_t)bh * 2048 + tq) * 64;
  const _Float16* kg = kh + ((size_t)bh * 2048 + tk) * 64;

  if (tid < 128) invs[tid] = invp[(size_t)bh * 2048 + tq + tid];

#pragma unroll
  for (int rnd = 0; rnd < 4; ++rnd) {
    const int seg = w * 4 + rnd;
    const int row = seg * 8 + (l >> 3);
    const int ss = (l & 7) ^ (row & 7);
    load_lds16(qg + (size_t)row * 64 + ss * 8, Qs + seg * 512 + l * 8);
    load_lds16(kg + (size_t)row * 64 + ss * 8, Ks + seg * 512 + l * 8);
  }
  __syncthreads();

  const int wr = w >> 1, wc = w & 1;
  f32x4 acc[4][4];
#pragma unroll
  for (int i = 0; i < 4; ++i)
#pragma unroll
    for (int j = 0; j < 4; ++j) acc[i][j] = (f32x4){0.f, 0.f, 0.f, 0.f};

#pragma unroll
  for (int dh = 0; dh < 2; ++dh) {
    half8 af[4], bf[4];
#pragma unroll
    for (int mt = 0; mt < 4; ++mt) {
      const int row = wr * 64 + mt * 16 + c;
      af[mt] = *(const half8*)(Qs + row * 64 + (((dh * 4 + g) ^ (row & 7)) * 8));
    }
#pragma unroll
    for (int nt = 0; nt < 4; ++nt) {
      const int row = wc * 64 + nt * 16 + c;
      bf[nt] = *(const half8*)(Ks + row * 64 + (((dh * 4 + g) ^ (row & 7)) * 8));
    }
#pragma unroll
    for (int mt = 0; mt < 4; ++mt)
#pragma unroll
      for (int nt = 0; nt < 4; ++nt)
        acc[mt][nt] = MFMA16(af[mt], bf[nt], acc[mt][nt]);
  }

  // epilogue: per mt, stage 32 rows x 128 cols f32 in LDS, stream f32x4
#pragma unroll 1
  for (int mt = 0; mt < 4; ++mt) {
    const int lrow = wr * 16 + 4 * g;  // + r
#pragma unroll
    for (int nt = 0; nt < 4; ++nt) {
      const int col = wc * 64 + nt * 16 + c;
#pragma unroll
      for (int r = 0; r < 4; ++r) {
        const float iv = invs[wr * 64 + mt * 16 + 4 * g + r];
        stg[lrow + r][col] = __expf(acc[mt][nt][r] * 0.125f) * iv;
      }
    }
    __syncthreads();
#pragma unroll
    for (int i = 0; i < 4; ++i) {
      const int idx = i * 256 + tid;      // 1024 f32x4s
      const int row = idx >> 5, col4 = idx & 31;
      const int grow = (row < 16) ? (mt * 16 + row) : (64 + mt * 16 + row - 16);
      f32x4 v = *(const f32x4*)(&stg[row][col4 * 4]);
      __builtin_nontemporal_store(
          v, (f32x4*)(wout + ((size_t)bh * 2048 + tq + grow) * 2048 + tk) + col4);
    }
    __syncthreads();
  }
}

// ---------------------------------------------------------------------------
extern "C" void kernel_launch(void* const* d_in, const int* in_sizes, int n_in,
                              void* d_out, int out_size, void* d_ws, size_t ws_size,
                              hipStream_t stream) {
  const float* Q  = (const float*)d_in[0];
  const float* Kx = (const float*)d_in[1];
  const float* V  = (const float*)d_in[2];
  const float* wq = (const float*)d_in[3];
  const float* bq = (const float*)d_in[4];
  const float* wk = (const float*)d_in[5];
  const float* bk = (const float*)d_in[6];
  const float* wv = (const float*)d_in[7];
  const float* bv = (const float*)d_in[8];
  const float* wo = (const float*)d_in[9];
  const float* bo = (const float*)d_in[10];

  float* out  = (float*)d_out;
  float* wout = out + (size_t)4194304;

  char* ws = (char*)d_ws;
  const size_t MB = 1024 * 1024;
  _Float16* Xq  = (_Float16*)(ws + 0 * MB);
  _Float16* Xk  = (_Float16*)(ws + 8 * MB);
  _Float16* Xv  = (_Float16*)(ws + 16 * MB);
  _Float16* wqT = (_Float16*)(ws + 24 * MB);
  _Float16* wkT = (_Float16*)(ws + 26 * MB);
  _Float16* wvT = (_Float16*)(ws + 28 * MB);
  _Float16* woT = (_Float16*)(ws + 30 * MB);
  _Float16* qhp = (_Float16*)(ws + 32 * MB);
  _Float16* khp = (_Float16*)(ws + 40 * MB);
  _Float16* vTp = (_Float16*)(ws + 48 * MB);
  _Float16* cat = (_Float16*)(ws + 56 * MB);
  float*    invp = (float*)(ws + 16 * MB);  // reuses Xv (dead after QKV GEMM)

  cvt_f16_kernel<<<dim3(2048, 3), 256, 0, stream>>>(Q, Kx, V, Xq, Xk, Xv);
  transpose_cvt_kernel<<<dim3(16, 16, 4), 256, 0, stream>>>(
      wq, wk, wv, wo, wqT, wkT, wvT, woT);

  GemmArgs qkv;
  qkv.A[0] = Xq;  qkv.A[1] = Xk;  qkv.A[2] = Xv;
  qkv.BT[0] = wqT; qkv.BT[1] = wkT; qkv.BT[2] = wvT;
  qkv.bias[0] = bq; qkv.bias[1] = bk; qkv.bias[2] = bv;
  qkv.out[0] = qhp; qkv.out[1] = khp; qkv.out[2] = vTp;
  gemm_f16_kernel<<<dim3(8, 32, 3), 256, 0, stream>>>(qkv, 1024, 0x100);

  pv_kernel<<<dim3(32, 16, 2), 256, 0, stream>>>(qhp, khp, vTp, invp, cat);
  wts_kernel<<<dim3(16, 16, 32), 256, 0, stream>>>(qhp, khp, invp, wout);

  GemmArgs og;
  og.A[0] = cat; og.A[1] = cat; og.A[2] = cat;
  og.BT[0] = woT; og.BT[1] = woT; og.BT[2] = woT;
  og.bias[0] = bo; og.bias[1] = bo; og.bias[2] = bo;
  og.out[0] = out; og.out[1] = out; og.out[2] = out;
  gemm_f16_kernel<<<dim3(8, 32, 1), 256, 0, stream>>>(og, 1024, 0x2);
}